// Round 7
// baseline (365.070 us; speedup 1.0000x reference)
//
#include <hip/hip_runtime.h>

// ODENet forward, round 20: r19 W31-fusion math (VALIDATED: absmax 0.046875
// == r17 RK3) with the register spill fixed. r19 spilled (FETCH 226MB,
// WRITE 150MB scratch traffic, ode 195us): Z1+ZA+M+D = 128 f32 live on top
// of 128 weight VGPRs. Fixes, math identical:
//  (a) ZA eliminated: Z1 <- Z1 - D1 in place after h1_2 store (-32 regs).
//  (b) every heavy phase split into mb-halves i=0,1: accumulator 16 regs
//      consumed before i=1 begins; B-frags reloaded per half (+8
//      ds_read_b128/phase, measured-cheap); sched_barrier(0) between
//      halves pins the liveness split.
//  (c) WA1t/WAlt loads moved inside U-phase passes; W3t issued between
//      s3's i-halves (latency hidden under MFMAs, liveness short).
// Peak ~224+addr < 256/wave budget. Spill tell = FETCH/WRITE inflation.
// z-space recurrence (r19): z1(S_{j+1}) = z1(y) + c*(h2@W31 + b31) with
// W31 = W3@W1; 128-dim state never materialized; stage 3 = L2 only;
// epilogue pred = x@Wl + (M/6)@W3l + (bl + b3@Wl), M = h2_1+4h2_2+h2_3.
// Barriers/tile 8 (vs r17's 11).
// Core (validated r16/r17): b128 B-frags, lgkm-only barriers, raw[2] async
// x prefetch, f16 MFMA 16x16x32, ping-pong 2x32KB, grid 256 persistent,
// 4 row-tiles/WG.
// HISTORY (do not regress): r5 launch_bounds(512,4) -> weight spill; r8
// inline f32 gather -> spill; r11 LDS union overlays -> divergence; r13
// full-unroll float4 epilogue -> +23us; r18 RK2 -> absmax fail (0.1406);
// r19 Z1+ZA+M+D live -> 384MB scratch spill.

typedef _Float16 half8 __attribute__((ext_vector_type(8)));
typedef _Float16 half4 __attribute__((ext_vector_type(4)));
typedef float    floatx4 __attribute__((ext_vector_type(4)));

#define MFMA16 __builtin_amdgcn_mfma_f32_16x16x32_f16

constexpr int DDIM  = 118;
constexpr int TILES = 4;      // row-tiles of 64 per WG (grid 256)

// async global->LDS, 16B/lane, LDS dest = wave-uniform base + lane*16
#define GLOAD_LDS16(g, p) __builtin_amdgcn_global_load_lds(              \
    (const __attribute__((address_space(1))) void*)(g),                  \
    (__attribute__((address_space(3))) void*)(p), 16, 0, 0)

// LDS-producer/consumer barrier WITHOUT vmcnt drain.
#define BAR_LGKM() do {                                                  \
    asm volatile("s_waitcnt lgkmcnt(0)" ::: "memory");                   \
    __builtin_amdgcn_s_barrier();                                        \
    asm volatile("" ::: "memory");                                       \
  } while (0)

#define SCHED_FENCE() __builtin_amdgcn_sched_barrier(0)

// B-fragment: frag(kc,nb) = 64 lanes x 8 f16; lane l holds
// (k = 32kc + 8(l>>4) + t, n = 16nb + (l&15)), t=0..7.
__device__ __forceinline__ int FRAGB(int kc, int nb) {
  return (kc*4 + nb) * 512;
}

struct SMemT {
  _Float16 b[2][16384];   // ping-pong activation buffers, 32KB each
  float raw[2][7552];     // x staging, double-buffered async prefetch
  float epi_x[16 * 66];   // x@Wl + blsum, rows o=0..15 (4224B)
  float cb1[256];         // b1
  float cb2[256];         // b2
  float cb31[256];        // b31 = b3@W1
  float cbls[10];         // blsum = bl + b3@Wl
};                        // total ~133.3KB < 160KB/CU

// ---- pack A1/A2: fp32 W[K][N] (k-major) -> A-frag f16 ----
__global__ void pack_weights_all(const float* __restrict__ W1,
                                 const float* __restrict__ W2,
                                 _Float16* __restrict__ out)
{
  int idx = blockIdx.x * 256 + threadIdx.x;     // 0 .. 98303
  const float* W; int kcBits, base;
  if (idx < 32768) { W = W1; kcBits = 2; base = 0;     }
  else             { W = W2; kcBits = 3; base = 32768; }
  int rel = idx - base;
  int j  = rel & 7;
  int L  = (rel >> 3) & 63;
  int blk = rel >> 9;
  int kc = blk & ((1 << kcBits) - 1);
  int mb = blk >> kcBits;
  int k = 32*kc + 8*(L >> 4) + j;
  int m = 16*mb + (L & 15);
  out[idx] = (_Float16)W[k*256 + m];
}

// ---- fuse: W31 = W3@W1 frags, W3lf/Wlf frags, b31, blsum (r19-validated) --
__global__ void fuse_weights(const float* __restrict__ W1,
                             const float* __restrict__ W3,
                             const float* __restrict__ Wl,
                             const float* __restrict__ b3,
                             const float* __restrict__ bl,
                             _Float16* __restrict__ fr,
                             float* __restrict__ b31o,
                             float* __restrict__ blso)
{
  __shared__ float w3row[128];
  const int tid = threadIdx.x;
  const int blk = blockIdx.x;
  if (blk < 256) {
    const int k = blk;                       // h2-dim row of W31
    if (tid < 128) w3row[tid] = W3[k*128 + tid];
    __syncthreads();
    float acc = 0.f;
    for (int j = 0; j < 128; ++j) acc = fmaf(w3row[j], W1[j*256 + tid], acc);
    {
      int m = tid;
      int mb = m >> 4, kc = k >> 5, j7 = k & 7;
      int L = ((k & 31) >> 3) * 16 + (m & 15);
      fr[98304 + ((mb*8 + kc)*64 + L)*8 + j7] = (_Float16)acc;
    }
    if (tid < 16) {
      float a2 = 0.f;
      if (tid < 10)
        for (int j = 0; j < 128; ++j) a2 = fmaf(w3row[j], Wl[j*10 + tid], a2);
      int kc = k >> 5, j7 = k & 7;
      int L = ((k & 31) >> 3) * 16 + tid;
      fr[165888 + (kc*64 + L)*8 + j7] = (_Float16)a2;
    }
  } else if (blk == 256) {
    float acc = 0.f;
    for (int j = 0; j < 128; ++j) acc = fmaf(b3[j], W1[j*256 + tid], acc);
    b31o[tid] = acc;
    if (tid < 10) {
      float a2 = bl[tid];
      for (int j = 0; j < 128; ++j) a2 = fmaf(b3[j], Wl[j*10 + tid], a2);
      blso[tid] = a2;
    }
  } else {
    for (int e = tid; e < 2048; e += 256) {
      int k = e >> 4, m = e & 15;
      float v = (m < 10) ? Wl[k*10 + m] : 0.f;
      int kc = k >> 5, j7 = k & 7;
      int L = ((k & 31) >> 3) * 16 + m;
      fr[163840 + (kc*64 + L)*8 + j7] = (_Float16)v;
    }
  }
}

__global__ __launch_bounds__(512, 2)
void ode_kernel(const float* __restrict__ x,
                const float* __restrict__ b1v, const float* __restrict__ b2v,
                const _Float16* __restrict__ Aw,
                const float* __restrict__ b31g, const float* __restrict__ blsg,
                float* __restrict__ out)
{
  __shared__ SMemT sm;
  const int tid = threadIdx.x;
  const int w   = tid >> 6;    // wave 0..7
  const int l   = tid & 63;
  const int q   = l >> 4;
  const int c   = l & 15;

  const int sh  = q & 1;       // store-side half (t = 4*sh + r)
  const int qh  = q >> 1;
  const int lb  = l * 8;       // lane's B-frag offset (f16 units)

  // ---- issue async prefetch of tile 0's x block ----
  {
    const float* src = x + (size_t)(blockIdx.x * (64 * TILES)) * DDIM;
    float* dst = sm.raw[0];
    for (int ch = w; ch < 30; ch += 8) {
      int idx = ch * 64 + l;
      if (idx < 1888) GLOAD_LDS16(src + (size_t)idx * 4, dst + ch * 256);
    }
  }

  // ---- stage constants into LDS (once per WG) ----
  if (tid < 256) {
    sm.cb1[tid]  = b1v[tid];
    sm.cb2[tid]  = b2v[tid];
    sm.cb31[tid] = b31g[tid];
  }
  if (tid < 10) sm.cbls[tid] = blsg[tid];

  // ---- persistent weight A-frags: WA2 + W31f = 128 VGPRs/wave ----
  const _Float16* A2  = Aw + 32768;
  const _Float16* A31 = Aw + 98304;
  half8 WA2[2][8], W31f[2][8];
#pragma unroll
  for (int i = 0; i < 2; ++i)
#pragma unroll
    for (int kc = 0; kc < 8; ++kc) {
      WA2[i][kc]  = *(const half8*)&A2 [((((2*w+i)*8 + kc)*64) + l)*8];
      W31f[i][kc] = *(const half8*)&A31[((((2*w+i)*8 + kc)*64) + l)*8];
    }

  const _Float16* A1  = Aw;            // 16mb x 4kc
  const _Float16* Awl = Aw + 163840;   // Wlf  (1mb x 4kc)
  const _Float16* A3l = Aw + 165888;   // W3lf (1mb x 8kc)

#pragma unroll 1
  for (int t = 0; t < TILES; ++t) {
    const int R = blockIdx.x * (64 * TILES) + t * 64;
    const float* rawc = sm.raw[t & 1];

    // drain this tile's prefetch; fence LDS reuse
    asm volatile("s_waitcnt vmcnt(0)" ::: "memory");
    BAR_LGKM();

    // ---- issue NEXT tile's prefetch ----
    if (t + 1 < TILES) {
      const float* src = x + (size_t)(R + 64) * DDIM;
      float* dst = sm.raw[(t + 1) & 1];
      for (int ch = w; ch < 30; ch += 8) {
        int idx = ch * 64 + l;
        if (idx < 1888) GLOAD_LDS16(src + (size_t)idx * 4, dst + ch * 256);
      }
    }

    // ---- build x_aug frags in b[0] (kc<4, zero-pad k>=118) ----
    for (int g = tid; g < 1024; g += 512) {
      int ll = g & 63;
      int nb = (g >> 6) & 3;
      int kc = g >> 8;
      int n  = 16*nb + (ll & 15);
      int k0 = 32*kc + 8*(ll >> 4);
      half8 v;
#pragma unroll
      for (int tt = 0; tt < 8; ++tt) {
        int k = k0 + tt;
        v[tt] = (_Float16)((k < DDIM) ? rawc[n*DDIM + k] : 0.0f);
      }
      *(half8*)&sm.b[0][FRAGB(kc, nb) + ll*8] = v;
    }
    BAR_LGKM();        // x frags ready

    floatx4 Z1[2][4];  // z1(y) (f32, persistent this tile; becomes ZA)
    floatx4 M[2][4];   // h2_1 + 4 h2_2 (+ h2_3 at s3)

    // ==== U phase: Z1 = x@W1 + b1 (i-split); CP = x@Wl + blsum ====
#pragma unroll
    for (int i = 0; i < 2; ++i) {
      half8 WA1t[4];
#pragma unroll
      for (int kc = 0; kc < 4; ++kc)
        WA1t[kc] = *(const half8*)&A1[((((2*w+i)*4 + kc)*64) + l)*8];
      floatx4 Zi[4];
#pragma unroll
      for (int nb = 0; nb < 4; ++nb)
#pragma unroll
        for (int r = 0; r < 4; ++r)
          Zi[nb][r] = sm.cb1[32*w + 16*i + 4*q + r];
#pragma unroll
      for (int kc = 0; kc < 4; ++kc) {
        half8 bf[4];
#pragma unroll
        for (int nb = 0; nb < 4; ++nb)
          bf[nb] = *(const half8*)&sm.b[0][FRAGB(kc, nb) + lb];
#pragma unroll
        for (int nb = 0; nb < 4; ++nb)
          Zi[nb] = MFMA16(WA1t[kc], bf[nb], Zi[nb], 0, 0, 0);
      }
#pragma unroll
      for (int nb = 0; nb < 4; ++nb) {
        half4 v;
#pragma unroll
        for (int r = 0; r < 4; ++r) v[r] = (_Float16)fmaxf(Zi[nb][r], 0.0f);
        *(half4*)&sm.b[1][FRAGB(w, nb) + (16*(2*i+qh) + c)*8 + sh*4] = v;
        Z1[i][nb] = Zi[nb];
      }
      SCHED_FENCE();
    }
    {
      half8 WAlt[4];
#pragma unroll
      for (int kc = 0; kc < 4; ++kc)
        WAlt[kc] = *(const half8*)&Awl[(kc*64 + l)*8];
      floatx4 CP[4];
#pragma unroll
      for (int nb = 0; nb < 4; ++nb)
#pragma unroll
        for (int r = 0; r < 4; ++r) CP[nb][r] = sm.cbls[4*q + r];
#pragma unroll
      for (int kc = 0; kc < 4; ++kc) {
        half8 bf[4];
#pragma unroll
        for (int nb = 0; nb < 4; ++nb)
          bf[nb] = *(const half8*)&sm.b[0][FRAGB(kc, nb) + lb];
#pragma unroll
        for (int nb = 0; nb < 4; ++nb)
          CP[nb] = MFMA16(WAlt[kc], bf[nb], CP[nb], 0, 0, 0);
      }
      if (w == 0) {
#pragma unroll
        for (int nb = 0; nb < 4; ++nb)
#pragma unroll
          for (int r = 0; r < 4; ++r)
            sm.epi_x[(4*q + r)*66 + 16*nb + c] = CP[nb][r];
      }
      SCHED_FENCE();
    }
    BAR_LGKM();        // h1_1 + epi_x ready

    // ==== s1-L2 (i-split): h2_1 -> b[0]; M = h2_1 ====
#pragma unroll
    for (int i = 0; i < 2; ++i) {
      floatx4 C2[4];
#pragma unroll
      for (int nb = 0; nb < 4; ++nb)
#pragma unroll
        for (int r = 0; r < 4; ++r)
          C2[nb][r] = sm.cb2[32*w + 16*i + 4*q + r];
#pragma unroll
      for (int kc = 0; kc < 8; ++kc) {
        half8 bf[4];
#pragma unroll
        for (int nb = 0; nb < 4; ++nb)
          bf[nb] = *(const half8*)&sm.b[1][FRAGB(kc, nb) + lb];
#pragma unroll
        for (int nb = 0; nb < 4; ++nb)
          C2[nb] = MFMA16(WA2[i][kc], bf[nb], C2[nb], 0, 0, 0);
      }
#pragma unroll
      for (int nb = 0; nb < 4; ++nb) {
        half4 v;
#pragma unroll
        for (int r = 0; r < 4; ++r) {
          float hv = fmaxf(C2[nb][r], 0.0f);
          M[i][nb][r] = hv;
          v[r] = (_Float16)hv;
        }
        *(half4*)&sm.b[0][FRAGB(w, nb) + (16*(2*i+qh) + c)*8 + sh*4] = v;
      }
      SCHED_FENCE();
    }
    BAR_LGKM();        // h2_1 ready

    // ==== s1-W31 (i-split): D1; h1_2 = relu(Z1+.5D) -> b[1]; Z1 -= D ====
#pragma unroll
    for (int i = 0; i < 2; ++i) {
      floatx4 D[4];
#pragma unroll
      for (int nb = 0; nb < 4; ++nb)
#pragma unroll
        for (int r = 0; r < 4; ++r)
          D[nb][r] = sm.cb31[32*w + 16*i + 4*q + r];
#pragma unroll
      for (int kc = 0; kc < 8; ++kc) {
        half8 bf[4];
#pragma unroll
        for (int nb = 0; nb < 4; ++nb)
          bf[nb] = *(const half8*)&sm.b[0][FRAGB(kc, nb) + lb];
#pragma unroll
        for (int nb = 0; nb < 4; ++nb)
          D[nb] = MFMA16(W31f[i][kc], bf[nb], D[nb], 0, 0, 0);
      }
#pragma unroll
      for (int nb = 0; nb < 4; ++nb) {
        half4 v;
#pragma unroll
        for (int r = 0; r < 4; ++r) {
          float z = Z1[i][nb][r];
          float d = D[nb][r];
          v[r] = (_Float16)fmaxf(z + 0.5f*d, 0.0f);
          Z1[i][nb][r] = z - d;             // ZA in place
        }
        *(half4*)&sm.b[1][FRAGB(w, nb) + (16*(2*i+qh) + c)*8 + sh*4] = v;
      }
      SCHED_FENCE();
    }
    BAR_LGKM();        // h1_2 ready

    // ==== s2-L2 (i-split): h2_2 -> b[0]; M += 4 h2_2 ====
#pragma unroll
    for (int i = 0; i < 2; ++i) {
      floatx4 C2[4];
#pragma unroll
      for (int nb = 0; nb < 4; ++nb)
#pragma unroll
        for (int r = 0; r < 4; ++r)
          C2[nb][r] = sm.cb2[32*w + 16*i + 4*q + r];
#pragma unroll
      for (int kc = 0; kc < 8; ++kc) {
        half8 bf[4];
#pragma unroll
        for (int nb = 0; nb < 4; ++nb)
          bf[nb] = *(const half8*)&sm.b[1][FRAGB(kc, nb) + lb];
#pragma unroll
        for (int nb = 0; nb < 4; ++nb)
          C2[nb] = MFMA16(WA2[i][kc], bf[nb], C2[nb], 0, 0, 0);
      }
#pragma unroll
      for (int nb = 0; nb < 4; ++nb) {
        half4 v;
#pragma unroll
        for (int r = 0; r < 4; ++r) {
          float hv = fmaxf(C2[nb][r], 0.0f);
          M[i][nb][r] = fmaf(4.0f, hv, M[i][nb][r]);
          v[r] = (_Float16)hv;
        }
        *(half4*)&sm.b[0][FRAGB(w, nb) + (16*(2*i+qh) + c)*8 + sh*4] = v;
      }
      SCHED_FENCE();
    }
    BAR_LGKM();        // h2_2 ready

    // ==== s2-W31 (i-split): D2; h1_3 = relu(ZA + 2 D2) -> b[1] ====
#pragma unroll
    for (int i = 0; i < 2; ++i) {
      floatx4 D[4];
#pragma unroll
      for (int nb = 0; nb < 4; ++nb)
#pragma unroll
        for (int r = 0; r < 4; ++r)
          D[nb][r] = sm.cb31[32*w + 16*i + 4*q + r];
#pragma unroll
      for (int kc = 0; kc < 8; ++kc) {
        half8 bf[4];
#pragma unroll
        for (int nb = 0; nb < 4; ++nb)
          bf[nb] = *(const half8*)&sm.b[0][FRAGB(kc, nb) + lb];
#pragma unroll
        for (int nb = 0; nb < 4; ++nb)
          D[nb] = MFMA16(W31f[i][kc], bf[nb], D[nb], 0, 0, 0);
      }
#pragma unroll
      for (int nb = 0; nb < 4; ++nb) {
        half4 v;
#pragma unroll
        for (int r = 0; r < 4; ++r)
          v[r] = (_Float16)fmaxf(Z1[i][nb][r] + 2.0f*D[nb][r], 0.0f);
        *(half4*)&sm.b[1][FRAGB(w, nb) + (16*(2*i+qh) + c)*8 + sh*4] = v;
      }
      SCHED_FENCE();
    }
    BAR_LGKM();        // h1_3 ready

    // ==== s3-L2 (i-split): store (M + relu(C2))/6 -> b[0]; W3t mid-load ====
    half8 W3t[8];
#pragma unroll
    for (int i = 0; i < 2; ++i) {
      floatx4 C2[4];
#pragma unroll
      for (int nb = 0; nb < 4; ++nb)
#pragma unroll
        for (int r = 0; r < 4; ++r)
          C2[nb][r] = sm.cb2[32*w + 16*i + 4*q + r];
#pragma unroll
      for (int kc = 0; kc < 8; ++kc) {
        half8 bf[4];
#pragma unroll
        for (int nb = 0; nb < 4; ++nb)
          bf[nb] = *(const half8*)&sm.b[1][FRAGB(kc, nb) + lb];
#pragma unroll
        for (int nb = 0; nb < 4; ++nb)
          C2[nb] = MFMA16(WA2[i][kc], bf[nb], C2[nb], 0, 0, 0);
      }
#pragma unroll
      for (int nb = 0; nb < 4; ++nb) {
        half4 v;
#pragma unroll
        for (int r = 0; r < 4; ++r) {
          float mval = M[i][nb][r] + fmaxf(C2[nb][r], 0.0f);
          v[r] = (_Float16)(mval * (1.0f/6.0f));
        }
        *(half4*)&sm.b[0][FRAGB(w, nb) + (16*(2*i+qh) + c)*8 + sh*4] = v;
      }
      SCHED_FENCE();
      if (i == 0) {                       // issue W3t under i=1's MFMAs
#pragma unroll
        for (int kc = 0; kc < 8; ++kc)
          W3t[kc] = *(const half8*)&A3l[(kc*64 + l)*8];
      }
    }
    BAR_LGKM();        // M/6 frags ready

    // ==== M-proj: pred = epi_x + (M/6)@W3l; store (wave 0) ====
    {
      floatx4 CF[4];
#pragma unroll
      for (int nb = 0; nb < 4; ++nb)
#pragma unroll
        for (int r = 0; r < 4; ++r)
          CF[nb][r] = sm.epi_x[(4*q + r)*66 + 16*nb + c];
#pragma unroll
      for (int kc = 0; kc < 8; ++kc) {
        half8 bf[4];
#pragma unroll
        for (int nb = 0; nb < 4; ++nb)
          bf[nb] = *(const half8*)&sm.b[0][FRAGB(kc, nb) + lb];
#pragma unroll
        for (int nb = 0; nb < 4; ++nb)
          CF[nb] = MFMA16(W3t[kc], bf[nb], CF[nb], 0, 0, 0);
      }
      if (w == 0) {
#pragma unroll
        for (int nb = 0; nb < 4; ++nb)
#pragma unroll
          for (int r = 0; r < 4; ++r) {
            int o = 4*q + r;
            if (o < 10)
              out[(size_t)(R + 16*nb + c)*10 + o] = CF[nb][r];
          }
      }
    }
    // no trailing barrier: next tile-top vmcnt(0)+BAR_LGKM fences reuse
  }
}

extern "C" void kernel_launch(void* const* d_in, const int* in_sizes, int n_in,
                              void* d_out, int out_size, void* d_ws, size_t ws_size,
                              hipStream_t stream) {
  const float* x  = (const float*)d_in[0];
  const float* W1 = (const float*)d_in[1];
  const float* b1 = (const float*)d_in[2];
  const float* W2 = (const float*)d_in[3];
  const float* b2 = (const float*)d_in[4];
  const float* W3 = (const float*)d_in[5];
  const float* b3 = (const float*)d_in[6];
  const float* Wl = (const float*)d_in[7];
  const float* bl = (const float*)d_in[8];
  float* out = (float*)d_out;

  _Float16* Aw  = (_Float16*)d_ws;                       // f16 frags (~332KB)
  float*    wsf = (float*)((char*)d_ws + 339968);        // b31[256], blsum[10]

  pack_weights_all<<<384, 256, 0, stream>>>(W1, W2, Aw);
  fuse_weights<<<258, 256, 0, stream>>>(W1, W3, Wl, b3, bl, Aw, wsf, wsf + 256);
  ode_kernel<<<256, 512, 0, stream>>>(x, b1, b2, Aw, wsf, wsf + 256, out);
}

// Round 8
// 179.870 us; speedup vs baseline: 2.0296x; 2.0296x over previous
//
#include <hip/hip_runtime.h>

// ODENet forward, round 21: fat-wave re-tiling of the validated r17 RK3
// kernel. Diagnosis: r17 is LDS-PIPE-bound (8 waves x 80 B-frag reads x
// 1KB = 640KB/CU/stage through one 85B/cy pipe); B-traffic/wave scales as
// 1/(rows/wave), rows/wave was capped by the 256-reg budget at 2 waves/SIMD
// (512-thread WG). Fix: 256-thread WG (4 waves), launch_bounds(256,1) ->
// 1 wave/SIMD -> 512 unified VGPR+AGPR per wave. Each wave holds ALL
// weight frags (W1 64 + W2 128 + W3 64 = 256 regs, MFMA-operands ->
// AGPRs) and 2x output rows -> LDS traffic per CU HALVED (320 reads/stage).
// Same RK3 math (absmax 0.046875 validated r17), same phase structure.
// State trimmed: single K1A array (in-place K1 += 4*C3 after S3 uses old
// K1). Biases from LDS (cb1/cb2/cb3), not regs. Audit ~415/512.
// r19/r20 fusion abandoned: every variant peaked 220-250 regs vs the
// 256 cap at 2 waves/SIMD -> scratch spill (FETCH 226-265MB).
// Core (validated r16/r17): b128 B-frags, lgkm-only barriers, raw[2]
// async x prefetch via global_load_lds, f16 MFMA 16x16x32, fp32 state,
// ping-pong 2x32KB, grid 256 persistent, 4 row-tiles/WG, register-resident
// epilogue (shfl_xor q-reduce + 4-way LDS partials).
// HISTORY (do not regress): r5 8-wave launch_bounds(512,4) -> spill; r8
// inline f32 gather -> spill; r11 LDS union overlays -> divergence; r13
// full-unroll float4 epilogue -> +23us; r18 RK2 -> absmax fail 0.1406;
// r19/r20 W31-fusion at 2 waves/SIMD -> 384-503MB scratch spill.
// Spill tell: FETCH >> 30MB. Fallback: r17 (149.9us total).

typedef _Float16 half8 __attribute__((ext_vector_type(8)));
typedef _Float16 half4 __attribute__((ext_vector_type(4)));
typedef float    floatx4 __attribute__((ext_vector_type(4)));

#define MFMA16 __builtin_amdgcn_mfma_f32_16x16x32_f16

constexpr int DDIM  = 118;
constexpr int TILES = 4;      // row-tiles of 64 per WG (grid 256)

// async global->LDS, 16B/lane, LDS dest = wave-uniform base + lane*16
#define GLOAD_LDS16(g, p) __builtin_amdgcn_global_load_lds(              \
    (const __attribute__((address_space(1))) void*)(g),                  \
    (__attribute__((address_space(3))) void*)(p), 16, 0, 0)

// LDS-producer/consumer barrier WITHOUT vmcnt drain.
#define BAR_LGKM() do {                                                  \
    asm volatile("s_waitcnt lgkmcnt(0)" ::: "memory");                   \
    __builtin_amdgcn_s_barrier();                                        \
    asm volatile("" ::: "memory");                                       \
  } while (0)

// B-fragment: frag(kc,nb) = 64 lanes x 8 f16; lane l holds
// (k = 32kc + 8(l>>4) + t, n = 16nb + (l&15)), t=0..7.
__device__ __forceinline__ int FRAGB(int kc, int nb) {
  return (kc*4 + nb) * 512;
}

struct SMemT {
  _Float16 b[2][16384];   // ping-pong activation buffers, 32KB each
  float raw[2][7552];     // x staging, double-buffered async prefetch
  float wl[1280];         // Wl staged (5120B), [k][o] layout
  float part[4 * 10 * 66];// epilogue partials [w][o][pad66] (10560B)
  float bls[10];          // bl staged
  float cb1[256];         // b1
  float cb2[256];         // b2
  float cb3[128];         // b3
};                        // total ~143KB < 160KB/CU (1 WG/CU persistent)

// Fused pack: fp32 W[K][N] (k-major) -> A-fragment order f16 for all 3 mats.
// A1: 16mb x 4kc at out[0..32767]; A2: 16mb x 8kc at +32768; A3: 8mb x 8kc at +98304.
__global__ void pack_weights_all(const float* __restrict__ W1,
                                 const float* __restrict__ W2,
                                 const float* __restrict__ W3,
                                 _Float16* __restrict__ out)
{
  int idx = blockIdx.x * 256 + threadIdx.x;     // 0 .. 131071
  const float* W; int N, kcBits, base;
  if (idx < 32768)        { W = W1; N = 256; kcBits = 2; base = 0;     }
  else if (idx < 98304)   { W = W2; N = 256; kcBits = 3; base = 32768; }
  else                    { W = W3; N = 128; kcBits = 3; base = 98304; }
  int rel = idx - base;
  int j  = rel & 7;
  int L  = (rel >> 3) & 63;
  int blk = rel >> 9;
  int kc = blk & ((1 << kcBits) - 1);
  int mb = blk >> kcBits;
  int k = 32*kc + 8*(L >> 4) + j;
  int m = 16*mb + (L & 15);
  out[idx] = (_Float16)W[k*N + m];
}

__global__ __launch_bounds__(256, 1)
void ode_kernel(const float* __restrict__ x,
                const float* __restrict__ b1v, const float* __restrict__ b2v,
                const float* __restrict__ b3v,
                const float* __restrict__ Wl,  const float* __restrict__ bl,
                const _Float16* __restrict__ Aw, float* __restrict__ out)
{
  __shared__ SMemT sm;
  const int tid = threadIdx.x;
  const int w   = tid >> 6;    // wave 0..3
  const int l   = tid & 63;
  const int q   = l >> 4;
  const int c   = l & 15;

  const int sh  = q & 1;       // store-side half (t = 4*sh + r)
  const int qh  = q >> 1;
  const int lb  = l * 8;       // lane's B-frag offset (f16 units)

  // ---- issue async prefetch of tile 0's x block ----
  {
    const float* src = x + (size_t)(blockIdx.x * (64 * TILES)) * DDIM;
    float* dst = sm.raw[0];
    for (int ch = w; ch < 30; ch += 4) {        // 30 chunks of 64 float4
      int idx = ch * 64 + l;                    // float4 index, 1888 valid
      if (idx < 1888) GLOAD_LDS16(src + (size_t)idx * 4, dst + ch * 256);
    }
  }

  // ---- stage Wl/bl/biases into LDS (once per WG, coalesced) ----
  for (int i = tid; i < 1280; i += 256) sm.wl[i] = Wl[i];
  sm.cb1[tid] = b1v[tid];
  sm.cb2[tid] = b2v[tid];
  if (tid < 128) sm.cb3[tid] = b3v[tid];
  if (tid < 10)  sm.bls[tid] = bl[tid];

  // ---- weight A-fragments -> registers (ONCE per WG): 256 regs/wave ----
  // wave w owns: L1/L2 mb = 4w+i (i<4); L3 mb3 = 2w+i3 (i3<2)
  const _Float16* A1 = Aw;           // 16 mb x 4 kc
  const _Float16* A2 = Aw + 32768;   // 16 mb x 8 kc
  const _Float16* A3 = Aw + 98304;   //  8 mb x 8 kc
  half8 WA1[4][4], WA2[4][8], WA3[2][8];
#pragma unroll
  for (int i = 0; i < 4; ++i)
#pragma unroll
    for (int kc = 0; kc < 4; ++kc)
      WA1[i][kc] = *(const half8*)&A1[((((4*w+i)*4 + kc)*64) + l)*8];
#pragma unroll
  for (int i = 0; i < 4; ++i)
#pragma unroll
    for (int kc = 0; kc < 8; ++kc)
      WA2[i][kc] = *(const half8*)&A2[((((4*w+i)*8 + kc)*64) + l)*8];
#pragma unroll
  for (int i3 = 0; i3 < 2; ++i3)
#pragma unroll
    for (int kc = 0; kc < 8; ++kc)
      WA3[i3][kc] = *(const half8*)&A3[((((2*w+i3)*8 + kc)*64) + l)*8];

  const float h = 1.0f;        // single RK3 step over [0,1]

#pragma unroll 1
  for (int t = 0; t < TILES; ++t) {
    const int R = blockIdx.x * (64 * TILES) + t * 64;
    const float* rawc = sm.raw[t & 1];

    // drain this tile's prefetch (issued one full tile ago), fence LDS reuse
    asm volatile("s_waitcnt vmcnt(0)" ::: "memory");
    BAR_LGKM();        // raw[t&1] ready (t==0: also fences wl/bias staging)

    // ---- issue NEXT tile's prefetch into the other raw buffer ----
    if (t + 1 < TILES) {
      const float* src = x + (size_t)(R + 64) * DDIM;
      float* dst = sm.raw[(t + 1) & 1];
      for (int ch = w; ch < 30; ch += 4) {
        int idx = ch * 64 + l;
        if (idx < 1888) GLOAD_LDS16(src + (size_t)idx * 4, dst + ch * 256);
      }
    }

    // ---- build initial S in b[0] (b128 B-frag layout, zero-pad k>=118) --
    for (int g = tid; g < 1024; g += 256) {
      int ll = g & 63;
      int nb = (g >> 6) & 3;
      int kc = g >> 8;              // 0..3
      int n  = 16*nb + (ll & 15);
      int k0 = 32*kc + 8*(ll >> 4);
      half8 v;
#pragma unroll
      for (int tt = 0; tt < 8; ++tt) {
        int k = k0 + tt;
        v[tt] = (_Float16)((k < DDIM) ? rawc[n*DDIM + k] : 0.0f);
      }
      *(half8*)&sm.b[0][FRAGB(kc, nb) + ll*8] = v;
    }

    // ---- Y init (fp32): d = 32w + 16*i3 + 4q + r, n = 16nb + c ----
    float Y[2][4][4], K1A[2][4][4];
#pragma unroll
    for (int i3 = 0; i3 < 2; ++i3)
#pragma unroll
      for (int nb = 0; nb < 4; ++nb)
#pragma unroll
        for (int r = 0; r < 4; ++r) {
          int d = 32*w + 16*i3 + 4*q + r;
          int n = 16*nb + c;
          Y[i3][nb][r]   = (d < DDIM) ? rawc[n*DDIM + d] : 0.0f;
          K1A[i3][nb][r] = 0.0f;
        }
    BAR_LGKM();        // S ready

    // ---- RK3 (classic Kutta): S2 = y + h/2 k1; S3 = y + h(2k2 - k1);
    //      y' = y + h/6 (k1 + 4 k2 + k3) ----
#pragma unroll 1
    for (int it = 0; it < 3; ++it) {
      _Float16* P = sm.b[it & 1];         // holds S_it, receives H2
      _Float16* Q = sm.b[(it & 1) ^ 1];   // receives H1, then S_{it+1}

      // ---- layer 1: C1[i][nb], kc<4 (reads S from P) ----
      {
        floatx4 C1[4][4];
#pragma unroll
        for (int i = 0; i < 4; ++i)
#pragma unroll
          for (int nb = 0; nb < 4; ++nb)
#pragma unroll
            for (int r = 0; r < 4; ++r)
              C1[i][nb][r] = sm.cb1[16*(4*w+i) + 4*q + r];
#pragma unroll
        for (int kc = 0; kc < 4; ++kc) {
          half8 bf[4];
#pragma unroll
          for (int nb = 0; nb < 4; ++nb)
            bf[nb] = *(const half8*)&P[FRAGB(kc, nb) + lb];
#pragma unroll
          for (int i = 0; i < 4; ++i)
#pragma unroll
            for (int nb = 0; nb < 4; ++nb)
              C1[i][nb] = MFMA16(WA1[i][kc], bf[nb], C1[i][nb], 0, 0, 0);
        }
        // store H1 -> Q: mb=4w+i: frag(mb>>1, nb), lane 16*(2*(mb&1)+qh)+c
#pragma unroll
        for (int i = 0; i < 4; ++i) {
          const int kct = 2*w + (i >> 1);
          const int sq  = 2*(i & 1) + qh;
#pragma unroll
          for (int nb = 0; nb < 4; ++nb) {
            half4 v;
#pragma unroll
            for (int r = 0; r < 4; ++r) v[r] = (_Float16)fmaxf(C1[i][nb][r], 0.0f);
            *(half4*)&Q[FRAGB(kct, nb) + (16*sq + c)*8 + sh*4] = v;
          }
        }
      }
      BAR_LGKM();      // H1 ready (all layer-1 S reads done)

      // ---- layer 2: C2[i][nb], kc<8 (reads H1 from Q, writes H2 -> P) ----
      {
        floatx4 C2[4][4];
#pragma unroll
        for (int i = 0; i < 4; ++i)
#pragma unroll
          for (int nb = 0; nb < 4; ++nb)
#pragma unroll
            for (int r = 0; r < 4; ++r)
              C2[i][nb][r] = sm.cb2[16*(4*w+i) + 4*q + r];
#pragma unroll
        for (int kc = 0; kc < 8; ++kc) {
          half8 bf[4];
#pragma unroll
          for (int nb = 0; nb < 4; ++nb)
            bf[nb] = *(const half8*)&Q[FRAGB(kc, nb) + lb];
#pragma unroll
          for (int i = 0; i < 4; ++i)
#pragma unroll
            for (int nb = 0; nb < 4; ++nb)
              C2[i][nb] = MFMA16(WA2[i][kc], bf[nb], C2[i][nb], 0, 0, 0);
        }
#pragma unroll
        for (int i = 0; i < 4; ++i) {
          const int kct = 2*w + (i >> 1);
          const int sq  = 2*(i & 1) + qh;
#pragma unroll
          for (int nb = 0; nb < 4; ++nb) {
            half4 v;
#pragma unroll
            for (int r = 0; r < 4; ++r) v[r] = (_Float16)fmaxf(C2[i][nb][r], 0.0f);
            *(half4*)&P[FRAGB(kct, nb) + (16*sq + c)*8 + sh*4] = v;
          }
        }
      }
      BAR_LGKM();      // H2 ready (all layer-2 H1 reads done)

      // ---- layer 3: C3[i3][nb], kc<8 (reads H2 from P) ----
      floatx4 C3[2][4];
#pragma unroll
      for (int i3 = 0; i3 < 2; ++i3)
#pragma unroll
        for (int nb = 0; nb < 4; ++nb)
#pragma unroll
          for (int r = 0; r < 4; ++r)
            C3[i3][nb][r] = sm.cb3[16*(2*w+i3) + 4*q + r];
#pragma unroll
      for (int kc = 0; kc < 8; ++kc) {
        half8 bf[4];
#pragma unroll
        for (int nb = 0; nb < 4; ++nb)
          bf[nb] = *(const half8*)&P[FRAGB(kc, nb) + lb];
#pragma unroll
        for (int i3 = 0; i3 < 2; ++i3)
#pragma unroll
          for (int nb = 0; nb < 4; ++nb)
            C3[i3][nb] = MFMA16(WA3[i3][kc], bf[nb], C3[i3][nb], 0, 0, 0);
      }

      // ---- RK3 stage update; stages 0,1 write next S -> Q; stage 2 only
      //      updates Y in regs (store+barrier elided) ----
      // S'-store: mb3 = 2w+i3: frag(w, nb), lane 16*(2*i3+qh)+c, t=4sh+r
      if (it == 0) {
#pragma unroll
        for (int i3 = 0; i3 < 2; ++i3)
#pragma unroll
          for (int nb = 0; nb < 4; ++nb) {
            half4 v;
#pragma unroll
            for (int r = 0; r < 4; ++r) {
              float kv = C3[i3][nb][r];
              K1A[i3][nb][r] = kv;
              v[r] = (_Float16)(Y[i3][nb][r] + 0.5f * h * kv);
            }
            *(half4*)&Q[FRAGB(w, nb) + (16*(2*i3+qh) + c)*8 + sh*4] = v;
          }
        BAR_LGKM();    // S2 ready
      } else if (it == 1) {
#pragma unroll
        for (int i3 = 0; i3 < 2; ++i3)
#pragma unroll
          for (int nb = 0; nb < 4; ++nb) {
            half4 v;
#pragma unroll
            for (int r = 0; r < 4; ++r) {
              float kv = C3[i3][nb][r];
              float k1 = K1A[i3][nb][r];
              v[r] = (_Float16)(Y[i3][nb][r] + h * (2.0f * kv - k1));
              K1A[i3][nb][r] = k1 + 4.0f * kv;     // ACC in place
            }
            *(half4*)&Q[FRAGB(w, nb) + (16*(2*i3+qh) + c)*8 + sh*4] = v;
          }
        BAR_LGKM();    // S3 ready
      } else {
#pragma unroll
        for (int i3 = 0; i3 < 2; ++i3)
#pragma unroll
          for (int nb = 0; nb < 4; ++nb)
#pragma unroll
            for (int r = 0; r < 4; ++r)
              Y[i3][nb][r] += (h / 6.0f) * (K1A[i3][nb][r] + C3[i3][nb][r]);
        // no store, no barrier: epilogue's partials barrier fences b[] reuse
      }
    }

    // ---- epilogue: wave w's Y regs hold y[32w..32w+31][*] == its k-slice
    //      of y@Wl. Per-lane partial over (i3,r), shfl-reduce over q,
    //      4-way LDS partial sum. All fp32. ----
    {
      float acc[10][4];
#pragma unroll
      for (int o = 0; o < 10; ++o)
#pragma unroll
        for (int nb = 0; nb < 4; ++nb) acc[o][nb] = 0.0f;
#pragma unroll
      for (int i3 = 0; i3 < 2; ++i3)
#pragma unroll
        for (int r = 0; r < 4; ++r) {
          const float* wr = &sm.wl[(32*w + 16*i3 + 4*q + r) * 10];
          float wv[10];
#pragma unroll
          for (int o = 0; o < 10; ++o) wv[o] = wr[o];
#pragma unroll
          for (int o = 0; o < 10; ++o)
#pragma unroll
            for (int nb = 0; nb < 4; ++nb)
              acc[o][nb] = fmaf(Y[i3][nb][r], wv[o], acc[o][nb]);
        }
#pragma unroll
      for (int o = 0; o < 10; ++o)
#pragma unroll
        for (int nb = 0; nb < 4; ++nb) {
          float s = acc[o][nb];
          s += __shfl_xor(s, 16);
          s += __shfl_xor(s, 32);
          acc[o][nb] = s;
        }
      if (q == 0) {
#pragma unroll
        for (int o = 0; o < 10; ++o)
#pragma unroll
          for (int nb = 0; nb < 4; ++nb)
            sm.part[(w*10 + o)*66 + 16*nb + c] = acc[o][nb];
      }
    }
    BAR_LGKM();        // partials ready (also fences this tile's b[] reads)
    for (int u = tid; u < 640; u += 256) {
      int row = u / 10;              // n within tile
      int o   = u - row * 10;
      float s = sm.bls[o];
#pragma unroll
      for (int ww = 0; ww < 4; ++ww)
        s += sm.part[(ww*10 + o)*66 + row];
      out[(size_t)(R + row)*10 + o] = s;
    }
    // no trailing barrier: loop-top vmcnt(0)+BAR_LGKM fences reuse
  }
}

extern "C" void kernel_launch(void* const* d_in, const int* in_sizes, int n_in,
                              void* d_out, int out_size, void* d_ws, size_t ws_size,
                              hipStream_t stream) {
  const float* x  = (const float*)d_in[0];
  const float* W1 = (const float*)d_in[1];
  const float* b1 = (const float*)d_in[2];
  const float* W2 = (const float*)d_in[3];
  const float* b2 = (const float*)d_in[4];
  const float* W3 = (const float*)d_in[5];
  const float* b3 = (const float*)d_in[6];
  const float* Wl = (const float*)d_in[7];
  const float* bl = (const float*)d_in[8];
  float* out = (float*)d_out;

  _Float16* Aw = (_Float16*)d_ws;   // 262144 B

  pack_weights_all<<<512, 256, 0, stream>>>(W1, W2, W3, Aw);
  ode_kernel<<<256, 256, 0, stream>>>(x, b1, b2, b3, Wl, bl, Aw, out);
}

// Round 9
// 154.777 us; speedup vs baseline: 2.3587x; 1.1621x over previous
//
#include <hip/hip_runtime.h>

// ODENet forward, round 22: r17 RK3 kernel (validated best: ode 78us,
// absmax 0.046875) + pack_weights ELIMINATED: each wave gather-converts
// its own 32 weight A-fragments directly from fp32 W1/W2/W3 once per WG
// (per-j load is 4x64B-coalesced: lanes 0-15 read 16 consecutive floats).
// f32->f16 RNE conversion identical to pack's -> bit-identical numerics.
// sched_barrier(0) per fragment caps the unrolled gather's live-range
// (r8 lesson). Single kernel launch: removes pack dispatch + graph node +
// Aw workspace round-trip (theory: the ~72us total-vs-ode gap is partly
// pack; if total moves <5us the gap is harness-fixed and we're at plateau).
// r21 negative result (recorded): 4-wave/1-per-SIMD fat-wave = 110us ode
// despite halved LDS traffic -> stage loop is LATENCY-bound; keep 8 waves
// at 2/SIMD. r19/r20 W31-fusion: spills at 2-wave reg budget. r18 RK2:
// absmax fail 0.1406.
// Core (validated r16/r17): b128 B-frags (1 ds_read_b128/frag), lgkm-only
// barriers (no vmcnt drain in loop), register-resident epilogue (shfl_xor
// q-reduce + 8-way LDS partials), raw[2] async x prefetch via
// global_load_lds, f16 MFMA 16x16x32, fp32 state, RK3 N=1, ping-pong
// 2x32KB, grid 256 persistent, 4 row-tiles/WG.
// HISTORY (do not regress): r5 launch_bounds(512,4) -> weight spill; r8
// unfenced inline gather -> spill; r11 LDS union overlays -> divergence;
// r13 full-unroll float4 epilogue -> +23us; r21 fat-wave -> +32us.

typedef _Float16 half8 __attribute__((ext_vector_type(8)));
typedef _Float16 half4 __attribute__((ext_vector_type(4)));
typedef float    floatx4 __attribute__((ext_vector_type(4)));

#define MFMA16 __builtin_amdgcn_mfma_f32_16x16x32_f16

constexpr int DDIM  = 118;
constexpr int TILES = 4;      // row-tiles of 64 per WG (grid 256)

// async global->LDS, 16B/lane, LDS dest = wave-uniform base + lane*16
#define GLOAD_LDS16(g, p) __builtin_amdgcn_global_load_lds(              \
    (const __attribute__((address_space(1))) void*)(g),                  \
    (__attribute__((address_space(3))) void*)(p), 16, 0, 0)

// LDS-producer/consumer barrier WITHOUT vmcnt drain.
#define BAR_LGKM() do {                                                  \
    asm volatile("s_waitcnt lgkmcnt(0)" ::: "memory");                   \
    __builtin_amdgcn_s_barrier();                                        \
    asm volatile("" ::: "memory");                                       \
  } while (0)

#define SCHED_FENCE() __builtin_amdgcn_sched_barrier(0)

// B-fragment: frag(kc,nb) = 64 lanes x 8 f16; lane l holds
// (k = 32kc + 8(l>>4) + t, n = 16nb + (l&15)), t=0..7.
__device__ __forceinline__ int FRAGB(int kc, int nb) {
  return (kc*4 + nb) * 512;
}

struct SMemT {
  _Float16 b[2][16384];   // ping-pong activation buffers, 32KB each
  float raw[2][7552];     // x staging, double-buffered for async prefetch
  float wl[1280];         // Wl staged (5120B), [k][o] layout
  float part[8 * 10 * 66];// epilogue partials [w][o][pad66] (21120B)
  float bls[10];          // bl staged
};                        // total ~148.7KB < 160KB/CU (1 WG/CU persistent)

// gather one A-fragment: lane l, element j = W[(32*kc + 8*(l>>4) + j)*N
// + 16*mb + (l&15)]; per-j the 16 lanes of a c-group hit consecutive
// floats (64B segments) -> coalesced. RNE f32->f16 == pack kernel's.
__device__ __forceinline__ half8 gather_frag(const float* __restrict__ W,
                                             int N, int mb, int kc, int l) {
  const float* p = W + (size_t)(32*kc + 8*(l >> 4)) * N + 16*mb + (l & 15);
  half8 v;
#pragma unroll
  for (int j = 0; j < 8; ++j) v[j] = (_Float16)p[(size_t)j * N];
  return v;
}

__global__ __launch_bounds__(512, 2)
void ode_kernel(const float* __restrict__ x,
                const float* __restrict__ W1g, const float* __restrict__ b1v,
                const float* __restrict__ W2g, const float* __restrict__ b2v,
                const float* __restrict__ W3g, const float* __restrict__ b3v,
                const float* __restrict__ Wl,  const float* __restrict__ bl,
                float* __restrict__ out)
{
  __shared__ SMemT sm;
  const int tid = threadIdx.x;
  const int w   = tid >> 6;    // wave 0..7
  const int l   = tid & 63;
  const int q   = l >> 4;
  const int c   = l & 15;

  const int sh  = q & 1;       // store-side half (t = 4*sh + r)
  const int qh  = q >> 1;
  const int lb  = l * 8;       // lane's B-frag offset (f16 units)

  // ---- issue async prefetch of tile 0's x block (flies under gathers) ----
  {
    const float* src = x + (size_t)(blockIdx.x * (64 * TILES)) * DDIM;
    float* dst = sm.raw[0];
    for (int ch = w; ch < 30; ch += 8) {        // 30 chunks of 64 float4
      int idx = ch * 64 + l;                    // float4 index, 1888 valid
      if (idx < 1888) GLOAD_LDS16(src + (size_t)idx * 4, dst + ch * 256);
    }
  }

  // ---- stage Wl/bl into LDS (once per WG, coalesced) ----
  for (int i = tid; i < 1280; i += 512) sm.wl[i] = Wl[i];
  if (tid < 10) sm.bls[tid] = bl[tid];

  // ---- weight A-fragments: direct gather-convert from fp32 W (ONCE per
  //      WG, 128 VGPRs/wave resident). SCHED_FENCE per frag bounds the
  //      in-flight window so the unrolled nest can't balloon registers. ----
  half8 WA1[2][4], WA2[2][8], WA3[8];
#pragma unroll
  for (int i = 0; i < 2; ++i)
#pragma unroll
    for (int kc = 0; kc < 4; ++kc) {
      WA1[i][kc] = gather_frag(W1g, 256, 2*w + i, kc, l);
      SCHED_FENCE();
    }
#pragma unroll
  for (int i = 0; i < 2; ++i)
#pragma unroll
    for (int kc = 0; kc < 8; ++kc) {
      WA2[i][kc] = gather_frag(W2g, 256, 2*w + i, kc, l);
      SCHED_FENCE();
    }
#pragma unroll
  for (int kc = 0; kc < 8; ++kc) {
    WA3[kc] = gather_frag(W3g, 128, w, kc, l);
    SCHED_FENCE();
  }

  // ---- biases (per-lane; m = 16*mb + 4q + r), once per WG ----
  float bs1[2][4], bs2[2][4], bs3[4];
#pragma unroll
  for (int i = 0; i < 2; ++i)
#pragma unroll
    for (int r = 0; r < 4; ++r) {
      bs1[i][r] = b1v[16*(2*w+i) + 4*q + r];
      bs2[i][r] = b2v[16*(2*w+i) + 4*q + r];
    }
#pragma unroll
  for (int r = 0; r < 4; ++r) bs3[r] = b3v[16*w + 4*q + r];

  const float h = 1.0f;        // single RK3 step over [0,1]

#pragma unroll 1
  for (int t = 0; t < TILES; ++t) {
    const int R = blockIdx.x * (64 * TILES) + t * 64;
    const float* rawc = sm.raw[t & 1];

    // drain this tile's prefetch (issued one full tile ago), fence LDS reuse
    asm volatile("s_waitcnt vmcnt(0)" ::: "memory");
    BAR_LGKM();        // raw[t&1] ready (t==0: also fences wl/bl staging)

    // ---- issue NEXT tile's prefetch into the other raw buffer ----
    if (t + 1 < TILES) {
      const float* src = x + (size_t)(R + 64) * DDIM;
      float* dst = sm.raw[(t + 1) & 1];
      for (int ch = w; ch < 30; ch += 8) {
        int idx = ch * 64 + l;
        if (idx < 1888) GLOAD_LDS16(src + (size_t)idx * 4, dst + ch * 256);
      }
    }

    // ---- build initial S in b[0] (b128 B-frag layout, zero-pad k>=118) --
    for (int g = tid; g < 1024; g += 512) {
      int ll = g & 63;
      int nb = (g >> 6) & 3;
      int kc = g >> 8;              // 0..3
      int n  = 16*nb + (ll & 15);
      int k0 = 32*kc + 8*(ll >> 4);
      half8 v;
#pragma unroll
      for (int tt = 0; tt < 8; ++tt) {
        int k = k0 + tt;
        v[tt] = (_Float16)((k < DDIM) ? rawc[n*DDIM + k] : 0.0f);
      }
      *(half8*)&sm.b[0][FRAGB(kc, nb) + ll*8] = v;
    }

    // ---- Y init (fp32): d = 16w + 4q + r, n = 16nb + c ----
    float Y[4][4], K1[4][4], ACC[4][4];
#pragma unroll
    for (int nb = 0; nb < 4; ++nb)
#pragma unroll
      for (int r = 0; r < 4; ++r) {
        int d = 16*w + 4*q + r;
        int n = 16*nb + c;
        Y[nb][r]  = (d < DDIM) ? rawc[n*DDIM + d] : 0.0f;
        K1[nb][r] = 0.0f;
        ACC[nb][r] = 0.0f;
      }
    BAR_LGKM();        // S ready

    // ---- RK3 (classic Kutta): S2 = y + h/2 k1; S3 = y + h(2k2 - k1);
    //      y' = y + h/6 (k1 + 4 k2 + k3) ----
#pragma unroll 1
    for (int it = 0; it < 3; ++it) {
      _Float16* P = sm.b[it & 1];         // holds S_it, receives H2
      _Float16* Q = sm.b[(it & 1) ^ 1];   // receives H1, then S_{it+1}

      // ---- layer 1: C1[i][nb], kc<4 (reads S from P) ----
      {
        floatx4 C1[2][4];
#pragma unroll
        for (int i = 0; i < 2; ++i)
#pragma unroll
          for (int nb = 0; nb < 4; ++nb)
#pragma unroll
            for (int r = 0; r < 4; ++r) C1[i][nb][r] = bs1[i][r];
#pragma unroll
        for (int kc = 0; kc < 4; ++kc) {
          half8 bf[4];
#pragma unroll
          for (int nb = 0; nb < 4; ++nb)
            bf[nb] = *(const half8*)&P[FRAGB(kc, nb) + lb];
#pragma unroll
          for (int i = 0; i < 2; ++i)
#pragma unroll
            for (int nb = 0; nb < 4; ++nb)
              C1[i][nb] = MFMA16(WA1[i][kc], bf[nb], C1[i][nb], 0, 0, 0);
        }
        // store H1 -> Q: m=32w+16i+4q+r -> frag(w,nb), lane 16*(2i+qh)+c, t=4sh+r
#pragma unroll
        for (int i = 0; i < 2; ++i) {
#pragma unroll
          for (int nb = 0; nb < 4; ++nb) {
            half4 v;
#pragma unroll
            for (int r = 0; r < 4; ++r) v[r] = (_Float16)fmaxf(C1[i][nb][r], 0.0f);
            *(half4*)&Q[FRAGB(w, nb) + (16*(2*i+qh) + c)*8 + sh*4] = v;
          }
        }
      }
      BAR_LGKM();      // H1 ready (all layer-1 S reads done)

      // ---- layer 2: C2[i][nb], kc<8 (reads H1 from Q, writes H2 -> P) ----
      {
        floatx4 C2[2][4];
#pragma unroll
        for (int i = 0; i < 2; ++i)
#pragma unroll
          for (int nb = 0; nb < 4; ++nb)
#pragma unroll
            for (int r = 0; r < 4; ++r) C2[i][nb][r] = bs2[i][r];
#pragma unroll
        for (int kc = 0; kc < 8; ++kc) {
          half8 bf[4];
#pragma unroll
          for (int nb = 0; nb < 4; ++nb)
            bf[nb] = *(const half8*)&Q[FRAGB(kc, nb) + lb];
#pragma unroll
          for (int i = 0; i < 2; ++i)
#pragma unroll
            for (int nb = 0; nb < 4; ++nb)
              C2[i][nb] = MFMA16(WA2[i][kc], bf[nb], C2[i][nb], 0, 0, 0);
        }
#pragma unroll
        for (int i = 0; i < 2; ++i) {
#pragma unroll
          for (int nb = 0; nb < 4; ++nb) {
            half4 v;
#pragma unroll
            for (int r = 0; r < 4; ++r) v[r] = (_Float16)fmaxf(C2[i][nb][r], 0.0f);
            *(half4*)&P[FRAGB(w, nb) + (16*(2*i+qh) + c)*8 + sh*4] = v;
          }
        }
      }
      BAR_LGKM();      // H2 ready (all layer-2 H1 reads done)

      // ---- layer 3: C3[nb], kc<8 (reads H2 from P) ----
      floatx4 C3[4];
#pragma unroll
      for (int nb = 0; nb < 4; ++nb)
#pragma unroll
        for (int r = 0; r < 4; ++r) C3[nb][r] = bs3[r];
#pragma unroll
      for (int kc = 0; kc < 8; ++kc) {
        half8 bf[4];
#pragma unroll
        for (int nb = 0; nb < 4; ++nb)
          bf[nb] = *(const half8*)&P[FRAGB(kc, nb) + lb];
#pragma unroll
        for (int nb = 0; nb < 4; ++nb)
          C3[nb] = MFMA16(WA3[kc], bf[nb], C3[nb], 0, 0, 0);
      }

      // ---- RK3 stage update; stages 0,1 write next S -> Q; stage 2 only
      //      updates Y in regs (store+barrier elided: epilogue reads regs) --
      if (it == 0) {
#pragma unroll
        for (int nb = 0; nb < 4; ++nb) {
          half4 v;
#pragma unroll
          for (int r = 0; r < 4; ++r) {
            float kv = C3[nb][r];
            K1[nb][r] = kv;
            v[r] = (_Float16)(Y[nb][r] + 0.5f * h * kv);
          }
          *(half4*)&Q[FRAGB(w >> 1, nb) + (16*(2*(w&1)+qh) + c)*8 + sh*4] = v;
        }
        BAR_LGKM();    // S2 ready (H2 reads done)
      } else if (it == 1) {
#pragma unroll
        for (int nb = 0; nb < 4; ++nb) {
          half4 v;
#pragma unroll
          for (int r = 0; r < 4; ++r) {
            float kv = C3[nb][r];
            ACC[nb][r] = K1[nb][r] + 4.0f * kv;
            v[r] = (_Float16)(Y[nb][r] + h * (2.0f * kv - K1[nb][r]));
          }
          *(half4*)&Q[FRAGB(w >> 1, nb) + (16*(2*(w&1)+qh) + c)*8 + sh*4] = v;
        }
        BAR_LGKM();    // S3 ready (H2 reads done)
      } else {
#pragma unroll
        for (int nb = 0; nb < 4; ++nb)
#pragma unroll
          for (int r = 0; r < 4; ++r)
            Y[nb][r] += (h / 6.0f) * (ACC[nb][r] + C3[nb][r]);
        // no store, no barrier: epilogue's partials barrier fences b[] reuse
      }
    }

    // ---- epilogue: wave w's Y regs hold y[16w..16w+15][*] == its k-slice
    //      of y@Wl. Per-lane partial over r, shfl-reduce over q, 8-way
    //      LDS partial sum. All fp32; no transpose needed. ----
    {
      float acc[10][4];
#pragma unroll
      for (int o = 0; o < 10; ++o)
#pragma unroll
        for (int nb = 0; nb < 4; ++nb) acc[o][nb] = 0.0f;
#pragma unroll
      for (int r = 0; r < 4; ++r) {
        // wl row d = 16w+4q+r: 10 floats, broadcast within each c-group
        const float* wr = &sm.wl[(16*w + 4*q + r) * 10];
        float wv[10];
#pragma unroll
        for (int o = 0; o < 10; ++o) wv[o] = wr[o];
#pragma unroll
        for (int o = 0; o < 10; ++o)
#pragma unroll
          for (int nb = 0; nb < 4; ++nb)
            acc[o][nb] = fmaf(Y[nb][r], wv[o], acc[o][nb]);
      }
      // reduce over q (lane xor 16, 32); 40 independent sums
#pragma unroll
      for (int o = 0; o < 10; ++o)
#pragma unroll
        for (int nb = 0; nb < 4; ++nb) {
          float s = acc[o][nb];
          s += __shfl_xor(s, 16);
          s += __shfl_xor(s, 32);
          acc[o][nb] = s;
        }
      if (q == 0) {
#pragma unroll
        for (int o = 0; o < 10; ++o)
#pragma unroll
          for (int nb = 0; nb < 4; ++nb)
            sm.part[(w*10 + o)*66 + 16*nb + c] = acc[o][nb];
      }
    }
    BAR_LGKM();        // partials ready (also fences this tile's b[] reads)
    for (int u = tid; u < 640; u += 512) {
      int row = u / 10;              // n within tile
      int o   = u - row * 10;
      float s = sm.bls[o];
#pragma unroll
      for (int ww = 0; ww < 8; ++ww)
        s += sm.part[(ww*10 + o)*66 + row];
      out[(size_t)(R + row)*10 + o] = s;
    }
    // no trailing barrier: loop-top vmcnt(0)+BAR_LGKM fences reuse
  }
}

extern "C" void kernel_launch(void* const* d_in, const int* in_sizes, int n_in,
                              void* d_out, int out_size, void* d_ws, size_t ws_size,
                              hipStream_t stream) {
  const float* x  = (const float*)d_in[0];
  const float* W1 = (const float*)d_in[1];
  const float* b1 = (const float*)d_in[2];
  const float* W2 = (const float*)d_in[3];
  const float* b2 = (const float*)d_in[4];
  const float* W3 = (const float*)d_in[5];
  const float* b3 = (const float*)d_in[6];
  const float* Wl = (const float*)d_in[7];
  const float* bl = (const float*)d_in[8];
  float* out = (float*)d_out;

  // single kernel: weights gathered in-kernel, no pack pass, d_ws unused
  ode_kernel<<<256, 512, 0, stream>>>(x, W1, b1, W2, b2, W3, b3, Wl, bl, out);
}

// Round 10
// 151.256 us; speedup vs baseline: 2.4136x; 1.0233x over previous
//
#include <hip/hip_runtime.h>

// ODENet forward, round 23: r22 single-kernel (gather-in-kernel) with the
// gather FENCE GRANULARITY fixed. r22 post-mortem: fence-per-fragment
// serialized the weight gather into 32 dependent 8-load windows (~7us
// latency chain; ode 78->88). Fix: fence per 4 FRAGMENTS (8 fences total,
// 32 f32 temps in flight, peak ~190 regs < 256 budget -> no spill).
// Expected gather cost ~2us; single-kernel keeps the -5us node savings.
// r22 validated: in-kernel RNE f32->f16 gather is bit-identical (absmax
// 0.046875), no spill (FETCH 20.7MB), per-j loads 4x64B coalesced.
// r21 negative result: 4-wave/1-per-SIMD = +32us despite halved LDS
// traffic -> stage loop is LATENCY-bound; keep 8 waves at 2/SIMD.
// r19/r20: W31-fusion spills at 2-wave budget. r18: RK2 absmax fail.
// Core (validated r16/r17): b128 B-frags (1 ds_read_b128/frag), lgkm-only
// barriers (no vmcnt drain in loop), register-resident epilogue (shfl_xor
// q-reduce + 8-way LDS partials), raw[2] async x prefetch via
// global_load_lds, f16 MFMA 16x16x32, fp32 state, RK3 N=1, ping-pong
// 2x32KB, grid 256 persistent, 4 row-tiles/WG.
// HISTORY (do not regress): r5 launch_bounds(512,4) -> weight spill; r8
// UNFENCED inline gather -> ~50-reg spill (hence fences, but r22 showed
// per-frag is too fine); r11 LDS union overlays -> divergence; r13
// full-unroll float4 epilogue -> +23us; r21 fat-wave -> +32us.
// Plateau test: if total ~= 149-150 (r17's number), two structurally
// different kernels converge -> structural floor reached.

typedef _Float16 half8 __attribute__((ext_vector_type(8)));
typedef _Float16 half4 __attribute__((ext_vector_type(4)));
typedef float    floatx4 __attribute__((ext_vector_type(4)));

#define MFMA16 __builtin_amdgcn_mfma_f32_16x16x32_f16

constexpr int DDIM  = 118;
constexpr int TILES = 4;      // row-tiles of 64 per WG (grid 256)

// async global->LDS, 16B/lane, LDS dest = wave-uniform base + lane*16
#define GLOAD_LDS16(g, p) __builtin_amdgcn_global_load_lds(              \
    (const __attribute__((address_space(1))) void*)(g),                  \
    (__attribute__((address_space(3))) void*)(p), 16, 0, 0)

// LDS-producer/consumer barrier WITHOUT vmcnt drain.
#define BAR_LGKM() do {                                                  \
    asm volatile("s_waitcnt lgkmcnt(0)" ::: "memory");                   \
    __builtin_amdgcn_s_barrier();                                        \
    asm volatile("" ::: "memory");                                       \
  } while (0)

#define SCHED_FENCE() __builtin_amdgcn_sched_barrier(0)

// B-fragment: frag(kc,nb) = 64 lanes x 8 f16; lane l holds
// (k = 32kc + 8(l>>4) + t, n = 16nb + (l&15)), t=0..7.
__device__ __forceinline__ int FRAGB(int kc, int nb) {
  return (kc*4 + nb) * 512;
}

struct SMemT {
  _Float16 b[2][16384];   // ping-pong activation buffers, 32KB each
  float raw[2][7552];     // x staging, double-buffered for async prefetch
  float wl[1280];         // Wl staged (5120B), [k][o] layout
  float part[8 * 10 * 66];// epilogue partials [w][o][pad66] (21120B)
  float bls[10];          // bl staged
};                        // total ~148.7KB < 160KB/CU (1 WG/CU persistent)

// gather one A-fragment: lane l, element j = W[(32*kc + 8*(l>>4) + j)*N
// + 16*mb + (l&15)]; per-j the 16 lanes of a c-group hit consecutive
// floats (64B segments) -> coalesced. RNE f32->f16 == pack kernel's.
__device__ __forceinline__ half8 gather_frag(const float* __restrict__ W,
                                             int N, int mb, int kc, int l) {
  const float* p = W + (size_t)(32*kc + 8*(l >> 4)) * N + 16*mb + (l & 15);
  half8 v;
#pragma unroll
  for (int j = 0; j < 8; ++j) v[j] = (_Float16)p[(size_t)j * N];
  return v;
}

__global__ __launch_bounds__(512, 2)
void ode_kernel(const float* __restrict__ x,
                const float* __restrict__ W1g, const float* __restrict__ b1v,
                const float* __restrict__ W2g, const float* __restrict__ b2v,
                const float* __restrict__ W3g, const float* __restrict__ b3v,
                const float* __restrict__ Wl,  const float* __restrict__ bl,
                float* __restrict__ out)
{
  __shared__ SMemT sm;
  const int tid = threadIdx.x;
  const int w   = tid >> 6;    // wave 0..7
  const int l   = tid & 63;
  const int q   = l >> 4;
  const int c   = l & 15;

  const int sh  = q & 1;       // store-side half (t = 4*sh + r)
  const int qh  = q >> 1;
  const int lb  = l * 8;       // lane's B-frag offset (f16 units)

  // ---- issue async prefetch of tile 0's x block (flies under gathers) ----
  {
    const float* src = x + (size_t)(blockIdx.x * (64 * TILES)) * DDIM;
    float* dst = sm.raw[0];
    for (int ch = w; ch < 30; ch += 8) {        // 30 chunks of 64 float4
      int idx = ch * 64 + l;                    // float4 index, 1888 valid
      if (idx < 1888) GLOAD_LDS16(src + (size_t)idx * 4, dst + ch * 256);
    }
  }

  // ---- stage Wl/bl into LDS (once per WG, coalesced) ----
  for (int i = tid; i < 1280; i += 512) sm.wl[i] = Wl[i];
  if (tid < 10) sm.bls[tid] = bl[tid];

  // ---- biases (per-lane; m = 16*mb + 4q + r), once per WG ----
  float bs1[2][4], bs2[2][4], bs3[4];
#pragma unroll
  for (int i = 0; i < 2; ++i)
#pragma unroll
    for (int r = 0; r < 4; ++r) {
      bs1[i][r] = b1v[16*(2*w+i) + 4*q + r];
      bs2[i][r] = b2v[16*(2*w+i) + 4*q + r];
    }
#pragma unroll
  for (int r = 0; r < 4; ++r) bs3[r] = b3v[16*w + 4*q + r];

  // ---- weight A-fragments: direct gather-convert from fp32 W (ONCE per
  //      WG, 128 VGPRs/wave resident). Fence per 4 FRAGMENTS: 32-reg
  //      in-flight window (peak ~190 regs, no spill), 8 latency windows
  //      instead of r22's 32. ----
  half8 WA1[2][4], WA2[2][8], WA3[8];
#pragma unroll
  for (int i = 0; i < 2; ++i) {
#pragma unroll
    for (int kc = 0; kc < 4; ++kc)
      WA1[i][kc] = gather_frag(W1g, 256, 2*w + i, kc, l);
    SCHED_FENCE();
  }
#pragma unroll
  for (int i = 0; i < 2; ++i) {
#pragma unroll
    for (int kc = 0; kc < 8; ++kc) {
      WA2[i][kc] = gather_frag(W2g, 256, 2*w + i, kc, l);
      if ((kc & 3) == 3) SCHED_FENCE();
    }
  }
#pragma unroll
  for (int kc = 0; kc < 8; ++kc) {
    WA3[kc] = gather_frag(W3g, 128, w, kc, l);
    if ((kc & 3) == 3) SCHED_FENCE();
  }

  const float h = 1.0f;        // single RK3 step over [0,1]

#pragma unroll 1
  for (int t = 0; t < TILES; ++t) {
    const int R = blockIdx.x * (64 * TILES) + t * 64;
    const float* rawc = sm.raw[t & 1];

    // drain this tile's prefetch (issued one full tile ago), fence LDS reuse
    asm volatile("s_waitcnt vmcnt(0)" ::: "memory");
    BAR_LGKM();        // raw[t&1] ready (t==0: also fences wl/bl staging)

    // ---- issue NEXT tile's prefetch into the other raw buffer ----
    if (t + 1 < TILES) {
      const float* src = x + (size_t)(R + 64) * DDIM;
      float* dst = sm.raw[(t + 1) & 1];
      for (int ch = w; ch < 30; ch += 8) {
        int idx = ch * 64 + l;
        if (idx < 1888) GLOAD_LDS16(src + (size_t)idx * 4, dst + ch * 256);
      }
    }

    // ---- build initial S in b[0] (b128 B-frag layout, zero-pad k>=118) --
    for (int g = tid; g < 1024; g += 512) {
      int ll = g & 63;
      int nb = (g >> 6) & 3;
      int kc = g >> 8;              // 0..3
      int n  = 16*nb + (ll & 15);
      int k0 = 32*kc + 8*(ll >> 4);
      half8 v;
#pragma unroll
      for (int tt = 0; tt < 8; ++tt) {
        int k = k0 + tt;
        v[tt] = (_Float16)((k < DDIM) ? rawc[n*DDIM + k] : 0.0f);
      }
      *(half8*)&sm.b[0][FRAGB(kc, nb) + ll*8] = v;
    }

    // ---- Y init (fp32): d = 16w + 4q + r, n = 16nb + c ----
    float Y[4][4], K1[4][4], ACC[4][4];
#pragma unroll
    for (int nb = 0; nb < 4; ++nb)
#pragma unroll
      for (int r = 0; r < 4; ++r) {
        int d = 16*w + 4*q + r;
        int n = 16*nb + c;
        Y[nb][r]  = (d < DDIM) ? rawc[n*DDIM + d] : 0.0f;
        K1[nb][r] = 0.0f;
        ACC[nb][r] = 0.0f;
      }
    BAR_LGKM();        // S ready

    // ---- RK3 (classic Kutta): S2 = y + h/2 k1; S3 = y + h(2k2 - k1);
    //      y' = y + h/6 (k1 + 4 k2 + k3) ----
#pragma unroll 1
    for (int it = 0; it < 3; ++it) {
      const int s4 = it;
      _Float16* P = sm.b[it & 1];         // holds S_it, receives H2
      _Float16* Q = sm.b[(it & 1) ^ 1];   // receives H1, then S_{it+1}

      // ---- layer 1: C1[i][nb], kc<4 (reads S from P) ----
      {
        floatx4 C1[2][4];
#pragma unroll
        for (int i = 0; i < 2; ++i)
#pragma unroll
          for (int nb = 0; nb < 4; ++nb)
#pragma unroll
            for (int r = 0; r < 4; ++r) C1[i][nb][r] = bs1[i][r];
#pragma unroll
        for (int kc = 0; kc < 4; ++kc) {
          half8 bf[4];
#pragma unroll
          for (int nb = 0; nb < 4; ++nb)
            bf[nb] = *(const half8*)&P[FRAGB(kc, nb) + lb];
#pragma unroll
          for (int i = 0; i < 2; ++i)
#pragma unroll
            for (int nb = 0; nb < 4; ++nb)
              C1[i][nb] = MFMA16(WA1[i][kc], bf[nb], C1[i][nb], 0, 0, 0);
        }
        // store H1 -> Q: m=32w+16i+4q+r -> frag(w,nb), lane 16*(2i+qh)+c, t=4sh+r
#pragma unroll
        for (int i = 0; i < 2; ++i) {
#pragma unroll
          for (int nb = 0; nb < 4; ++nb) {
            half4 v;
#pragma unroll
            for (int r = 0; r < 4; ++r) v[r] = (_Float16)fmaxf(C1[i][nb][r], 0.0f);
            *(half4*)&Q[FRAGB(w, nb) + (16*(2*i+qh) + c)*8 + sh*4] = v;
          }
        }
      }
      BAR_LGKM();      // H1 ready (all layer-1 S reads done)

      // ---- layer 2: C2[i][nb], kc<8 (reads H1 from Q, writes H2 -> P) ----
      {
        floatx4 C2[2][4];
#pragma unroll
        for (int i = 0; i < 2; ++i)
#pragma unroll
          for (int nb = 0; nb < 4; ++nb)
#pragma unroll
            for (int r = 0; r < 4; ++r) C2[i][nb][r] = bs2[i][r];
#pragma unroll
        for (int kc = 0; kc < 8; ++kc) {
          half8 bf[4];
#pragma unroll
          for (int nb = 0; nb < 4; ++nb)
            bf[nb] = *(const half8*)&Q[FRAGB(kc, nb) + lb];
#pragma unroll
          for (int i = 0; i < 2; ++i)
#pragma unroll
            for (int nb = 0; nb < 4; ++nb)
              C2[i][nb] = MFMA16(WA2[i][kc], bf[nb], C2[i][nb], 0, 0, 0);
        }
#pragma unroll
        for (int i = 0; i < 2; ++i) {
#pragma unroll
          for (int nb = 0; nb < 4; ++nb) {
            half4 v;
#pragma unroll
            for (int r = 0; r < 4; ++r) v[r] = (_Float16)fmaxf(C2[i][nb][r], 0.0f);
            *(half4*)&P[FRAGB(w, nb) + (16*(2*i+qh) + c)*8 + sh*4] = v;
          }
        }
      }
      BAR_LGKM();      // H2 ready (all layer-2 H1 reads done)

      // ---- layer 3: C3[nb], kc<8 (reads H2 from P) ----
      floatx4 C3[4];
#pragma unroll
      for (int nb = 0; nb < 4; ++nb)
#pragma unroll
        for (int r = 0; r < 4; ++r) C3[nb][r] = bs3[r];
#pragma unroll
      for (int kc = 0; kc < 8; ++kc) {
        half8 bf[4];
#pragma unroll
        for (int nb = 0; nb < 4; ++nb)
          bf[nb] = *(const half8*)&P[FRAGB(kc, nb) + lb];
#pragma unroll
        for (int nb = 0; nb < 4; ++nb)
          C3[nb] = MFMA16(WA3[kc], bf[nb], C3[nb], 0, 0, 0);
      }

      // ---- RK3 stage update; stages 0,1 write next S -> Q; stage 2 only
      //      updates Y in regs (store+barrier elided: epilogue reads regs) --
      if (s4 == 0) {
#pragma unroll
        for (int nb = 0; nb < 4; ++nb) {
          half4 v;
#pragma unroll
          for (int r = 0; r < 4; ++r) {
            float kv = C3[nb][r];
            K1[nb][r] = kv;
            v[r] = (_Float16)(Y[nb][r] + 0.5f * h * kv);
          }
          *(half4*)&Q[FRAGB(w >> 1, nb) + (16*(2*(w&1)+qh) + c)*8 + sh*4] = v;
        }
        BAR_LGKM();    // S2 ready (H2 reads done)
      } else if (s4 == 1) {
#pragma unroll
        for (int nb = 0; nb < 4; ++nb) {
          half4 v;
#pragma unroll
          for (int r = 0; r < 4; ++r) {
            float kv = C3[nb][r];
            ACC[nb][r] = K1[nb][r] + 4.0f * kv;
            v[r] = (_Float16)(Y[nb][r] + h * (2.0f * kv - K1[nb][r]));
          }
          *(half4*)&Q[FRAGB(w >> 1, nb) + (16*(2*(w&1)+qh) + c)*8 + sh*4] = v;
        }
        BAR_LGKM();    // S3 ready (H2 reads done)
      } else {
#pragma unroll
        for (int nb = 0; nb < 4; ++nb)
#pragma unroll
          for (int r = 0; r < 4; ++r)
            Y[nb][r] += (h / 6.0f) * (ACC[nb][r] + C3[nb][r]);
        // no store, no barrier: epilogue's partials barrier fences b[] reuse
      }
    }

    // ---- epilogue: wave w's Y regs hold y[16w..16w+15][*] == its k-slice
    //      of y@Wl. Per-lane partial over r, shfl-reduce over q, 8-way
    //      LDS partial sum. All fp32; no transpose needed. ----
    {
      float acc[10][4];
#pragma unroll
      for (int o = 0; o < 10; ++o)
#pragma unroll
        for (int nb = 0; nb < 4; ++nb) acc[o][nb] = 0.0f;
#pragma unroll
      for (int r = 0; r < 4; ++r) {
        // wl row d = 16w+4q+r: 10 floats, broadcast within each c-group
        const float* wr = &sm.wl[(16*w + 4*q + r) * 10];
        float wv[10];
#pragma unroll
        for (int o = 0; o < 10; ++o) wv[o] = wr[o];
#pragma unroll
        for (int o = 0; o < 10; ++o)
#pragma unroll
          for (int nb = 0; nb < 4; ++nb)
            acc[o][nb] = fmaf(Y[nb][r], wv[o], acc[o][nb]);
      }
      // reduce over q (lane xor 16, 32); 40 independent sums
#pragma unroll
      for (int o = 0; o < 10; ++o)
#pragma unroll
        for (int nb = 0; nb < 4; ++nb) {
          float s = acc[o][nb];
          s += __shfl_xor(s, 16);
          s += __shfl_xor(s, 32);
          acc[o][nb] = s;
        }
      if (q == 0) {
#pragma unroll
        for (int o = 0; o < 10; ++o)
#pragma unroll
          for (int nb = 0; nb < 4; ++nb)
            sm.part[(w*10 + o)*66 + 16*nb + c] = acc[o][nb];
      }
    }
    BAR_LGKM();        // partials ready (also fences this tile's b[] reads)
    for (int u = tid; u < 640; u += 512) {
      int row = u / 10;              // n within tile
      int o   = u - row * 10;
      float s = sm.bls[o];
#pragma unroll
      for (int ww = 0; ww < 8; ++ww)
        s += sm.part[(ww*10 + o)*66 + row];
      out[(size_t)(R + row)*10 + o] = s;
    }
    // no trailing barrier: loop-top vmcnt(0)+BAR_LGKM fences reuse
  }
}

extern "C" void kernel_launch(void* const* d_in, const int* in_sizes, int n_in,
                              void* d_out, int out_size, void* d_ws, size_t ws_size,
                              hipStream_t stream) {
  const float* x  = (const float*)d_in[0];
  const float* W1 = (const float*)d_in[1];
  const float* b1 = (const float*)d_in[2];
  const float* W2 = (const float*)d_in[3];
  const float* b2 = (const float*)d_in[4];
  const float* W3 = (const float*)d_in[5];
  const float* b3 = (const float*)d_in[6];
  const float* Wl = (const float*)d_in[7];
  const float* bl = (const float*)d_in[8];
  float* out = (float*)d_out;

  // single kernel: weights gathered in-kernel, no pack pass, d_ws unused
  ode_kernel<<<256, 512, 0, stream>>>(x, W1, b1, W2, b2, W3, b3, Wl, bl, out);
}